// Round 15
// baseline (376.613 us; speedup 1.0000x reference)
//
#include <hip/hip_runtime.h>
#include <hip/hip_bf16.h>

#define BB 8
#define NN 2048
#define DD 128
#define TI 32     // i-rows per GEMM phase block
#define HP 132
#define CH 32
#define NC (NN / CH)   // 64
#define NO (NC + 1)    // 65
#define NFIX (BB * NO) // 520
#define GRID 512
#define TPB 256

__device__ __forceinline__ float relu(float x) { return x > 0.f ? x : 0.f; }

// Device-scope grid barrier (r11-proven). Safe: 512 blocks, 2 resident
// blocks/CU guaranteed by __launch_bounds__(256,2) (VGPR<=256 -> 8 waves/CU)
// and 44 KB LDS (2x44=88 <= 160 KB). One counter per phase, zeroed on-stream.
__device__ __forceinline__ void gridbar(unsigned* bar, int p) {
    __syncthreads();
    if (threadIdx.x == 0) {
        __threadfence();
        __hip_atomic_fetch_add(&bar[p], 1u, __ATOMIC_ACQ_REL, __HIP_MEMORY_SCOPE_AGENT);
        while (__hip_atomic_load(&bar[p], __ATOMIC_ACQUIRE, __HIP_MEMORY_SCOPE_AGENT) < GRID)
            __builtin_amdgcn_s_sleep(1);
        __threadfence();
    }
    __syncthreads();
}

__global__ __launch_bounds__(TPB, 2) void GraphAttentionalLayer_1168231104632_mega(
    const float* __restrict__ h,
    const float* __restrict__ W,
    const float* __restrict__ a,
    float* __restrict__ out,
    float* __restrict__ WT,  float* __restrict__ hw,
    float* __restrict__ E,   float* __restrict__ F,
    float* __restrict__ Fs,  float* __restrict__ zinv,
    int* __restrict__ perm,  int* __restrict__ kk,
    float* __restrict__ Q0L, float* __restrict__ Q1L,
    float* __restrict__ C0,  float* __restrict__ C1,
    float* __restrict__ O0,  float* __restrict__ O1,
    unsigned* __restrict__ bar)
{
    __shared__ float h_s[TI][HP];     // 16.9 KB (P1)
    __shared__ float wt_s[32][HP];    // 16.9 KB (P1)
    __shared__ float F_s[NN];         // 8 KB    (P2 unsorted, P4 sorted)
    __shared__ int   part[8][32];     // 1 KB    (P2)
    __shared__ float cf_s[NC];        //         (P4)
    __shared__ float of_s[NO];        //         (P4)
    __shared__ float T0s[DD], T1s[DD];//         (P5)

    const int tid = threadIdx.x;
    const int blk = blockIdx.x;

    // ============ P0: WT[d][e] = W[e][d] ============
    {
        const int g = blk * TPB + tid;
        if (g < DD * DD) {
            const int d = g >> 7, e = g & 127;
            WT[g] = W[e * DD + d];
        }
    }
    gridbar(bar, 0);

    // ============ P1: hw = h@W^T ; E=exp(si), F=exp(sj) (r13 verbatim) ============
    {
        const int t = tid & 127;
        const int hh = tid >> 7;
        const int tx = tid & 31, ty = tid >> 5;
        const int b = blk >> 6;
        const int i0 = (blk & 63) * TI;
        const size_t base = ((size_t)b * NN + i0) * DD;

        for (int r = hh; r < TI; r += 2)
            h_s[r][t] = h[base + (size_t)r * DD + t];

        const int e0 = tx * 4, r0 = ty * 4;
        float acc[4][4];
#pragma unroll
        for (int i = 0; i < 4; i++)
#pragma unroll
            for (int j = 0; j < 4; j++) acc[i][j] = 0.f;

        for (int dc = 0; dc < DD; dc += 32) {
            __syncthreads();
            for (int rr = hh; rr < 32; rr += 2)
                wt_s[rr][t] = WT[(size_t)(dc + rr) * DD + t];
            __syncthreads();
#pragma unroll 4
            for (int dd = 0; dd < 32; dd++) {
                const float4 wv = *reinterpret_cast<const float4*>(&wt_s[dd][e0]);
                const float w4[4] = {wv.x, wv.y, wv.z, wv.w};
#pragma unroll
                for (int r = 0; r < 4; r++) {
                    const float hv = h_s[r0 + r][dc + dd];
#pragma unroll
                    for (int e = 0; e < 4; e++) acc[r][e] += hv * w4[e];
                }
            }
        }

#pragma unroll
        for (int r = 0; r < 4; r++) {
            float4 o = make_float4(acc[r][0], acc[r][1], acc[r][2], acc[r][3]);
            *reinterpret_cast<float4*>(&hw[base + (size_t)(r0 + r) * DD + e0]) = o;
        }

        const float4 aiv = *reinterpret_cast<const float4*>(&a[e0]);
        const float4 ajv = *reinterpret_cast<const float4*>(&a[DD + e0]);
        const float ai4[4] = {aiv.x, aiv.y, aiv.z, aiv.w};
        const float aj4[4] = {ajv.x, ajv.y, ajv.z, ajv.w};
#pragma unroll
        for (int r = 0; r < 4; r++) {
            float pi = 0.f, pj = 0.f;
#pragma unroll
            for (int e = 0; e < 4; e++) { pi += acc[r][e] * ai4[e]; pj += acc[r][e] * aj4[e]; }
#pragma unroll
            for (int off = 16; off > 0; off >>= 1) {
                pi += __shfl_down(pi, off, 32);
                pj += __shfl_down(pj, off, 32);
            }
            if (tx == 0) {
                const size_t row = (size_t)b * NN + i0 + r0 + r;
                E[row] = __expf(pi);
                F[row] = __expf(pj);
            }
        }
    }
    gridbar(bar, 1);

    // ============ P2: rank-sort (32 j's/block, 8 slices; exact int counts) ============
    {
        const int b = blk >> 6;
        const int j0 = (blk & 63) * 32;
        const size_t nb = (size_t)b * NN;

        for (int q = 0; q < NN / TPB; q++)
            F_s[q * TPB + tid] = F[nb + q * TPB + tid];
        __syncthreads();

        const int tj = tid & 31, ts = tid >> 5;   // 8 slices of 256
        const int j = j0 + tj;
        const float fj = F_s[j];
        const int m0 = ts * (NN / 8);
        int cnt = 0;
#pragma unroll 8
        for (int mi = 0; mi < NN / 8; mi++) {
            const int m = m0 + mi;
            const float fm = F_s[m];
            cnt += (fm < fj) | ((fm == fj) & (m < j));
        }
        part[ts][tj] = cnt;
        __syncthreads();
        if (ts == 0) {
            int r = 0;
#pragma unroll
            for (int s = 0; s < 8; s++) r += part[s][tj];
            Fs[nb + r] = fj;
            perm[nb + r] = j;
        }
    }
    gridbar(bar, 2);

    // ============ P3: chunked prefix scans (r13 scan, tid<128) ============
    if (tid < 128) {
        const int t = tid;
        const int b = blk >> 6, c = blk & 63;
        const size_t nb = (size_t)b * NN;
        const int m0 = c * CH;

        int   jv[CH];
        float Fv[CH];
#pragma unroll
        for (int mm = 0; mm < CH; mm++) jv[mm] = perm[nb + m0 + mm];
#pragma unroll
        for (int mm = 0; mm < CH; mm++) Fv[mm] = Fs[nb + m0 + mm];

        float hv[CH];
#pragma unroll
        for (int mm = 0; mm < CH; mm++)
            hv[mm] = hw[(nb + jv[mm]) * DD + t];

        float a0 = 0.f, a1 = 0.f;
#pragma unroll
        for (int mm = 0; mm < CH; mm++) {
            const int m = m0 + mm;
            Q0L[(nb + m) * DD + t] = a0;
            Q1L[(nb + m) * DD + t] = a1;
            a0 += hv[mm];
            a1 += Fv[mm] * hv[mm];
        }
        C0[((size_t)b * NC + c) * DD + t] = a0;
        C1[((size_t)b * NC + c) * DD + t] = a1;
    }
    gridbar(bar, 3);

    // ============ P4: fix offsets (520 strided) + LDS search (blocks 0..63) ============
    {
        for (int idx = blk; idx < NFIX; idx += GRID) {
            const int b = idx / NO, c = idx % NO;
            const int d = tid & 127;
            const float* C = (tid < 128) ? C0 : C1;
            float*       O = (tid < 128) ? O0 : O1;
            float o = 0.f;
            int c2 = 0;
            for (; c2 + 16 <= c; c2 += 16) {
                float v[16];
#pragma unroll
                for (int q = 0; q < 16; q++)
                    v[q] = C[((size_t)b * NC + c2 + q) * DD + d];
#pragma unroll
                for (int q = 0; q < 16; q++) o += v[q];
            }
            for (; c2 < c; c2++)
                o += C[((size_t)b * NC + c2) * DD + d];
            O[((size_t)b * NO + c) * DD + d] = o;
        }

        if (blk < BB * 8) {
            const int b = blk >> 3;
            const int i0 = (blk & 7) * 256;
            const size_t nb = (size_t)b * NN;

            __syncthreads();
            for (int q = 0; q < NN / TPB; q++)
                F_s[q * TPB + tid] = Fs[nb + q * TPB + tid];
            __syncthreads();

            if (tid < NC) {
                float p = 0.f;
                const int m0 = tid * CH;
#pragma unroll
                for (int mm = 0; mm < CH; mm++) p += F_s[m0 + mm];
                cf_s[tid] = p;
            }
            __syncthreads();
            if (tid < NO) {
                float p = 0.f;
                for (int c2 = 0; c2 < tid; c2++) p += cf_s[c2];
                of_s[tid] = p;
            }
            __syncthreads();

            const int row = (int)nb + i0 + tid;
            const float Ei = E[row];
            const float thr = 1.0f / Ei;
            int lo = 0, hi = NN;
            while (lo < hi) {
                const int mid = (lo + hi) >> 1;
                if (F_s[mid] < thr) lo = mid + 1; else hi = mid;
            }
            float fpl = 0.f;
            for (int m = (lo >> 5) << 5; m < lo; m++) fpl += F_s[m];
            const float TF = of_s[NC];
            const float Pk = of_s[lo >> 5] + fpl;
            const float z = Ei * (TF - Pk) + (float)lo;
            kk[row] = lo;
            zinv[row] = 1.0f / z;
        }
    }
    gridbar(bar, 4);

    // ============ P5: output (32 rows/block, 2-row parallel) ============
    {
        const int t = tid & 127;
        const int g = tid >> 7;
        const int b = blk >> 6;
        const int rb = (blk & 63) * 32;
        const size_t nb = (size_t)b * NN;

        if (tid < DD) {
            T0s[tid] = O0[((size_t)b * NO + NC) * DD + tid];
            T1s[tid] = O1[((size_t)b * NO + NC) * DD + tid];
        }
        __syncthreads();

        for (int it = 0; it < 16; it++) {
            const int row = (int)nb + rb + it * 2 + g;
            const int k = kk[row];
            const float Ev = E[row];
            const float zv = zinv[row];
            float num;
            if (k < NN) {
                const int c = k >> 5;
                const float q0 = Q0L[(nb + k) * DD + t] + O0[((size_t)b * NO + c) * DD + t];
                const float q1 = Q1L[(nb + k) * DD + t] + O1[((size_t)b * NO + c) * DD + t];
                num = Ev * (T1s[t] - q1) + q0;
            } else {
                num = T0s[t];
            }
            out[(size_t)row * DD + t] = relu(num * zv);
        }
    }
}

extern "C" __attribute__((visibility("default")))
void kernel_launch(void* const* d_in, const int* in_sizes, int n_in,
                   void* d_out, int out_size, void* d_ws, size_t ws_size,
                   hipStream_t stream) {
    const float* h = nullptr; const float* W = nullptr; const float* a = nullptr;
    for (int i = 0; i < n_in; i++) {
        if (in_sizes[i] == BB * NN * DD)      h = (const float*)d_in[i];
        else if (in_sizes[i] == DD * DD)      W = (const float*)d_in[i];
        else if (in_sizes[i] == 2 * DD)       a = (const float*)d_in[i];
    }
    if (!h) h = (const float*)d_in[0];
    if (!W) W = (const float*)d_in[1];
    if (!a) a = (const float*)d_in[2];

    float* out = (float*)d_out;
    float* ws = (float*)d_ws;

    float* WT   = ws;                              // 16,384
    float* hw   = WT + DD * DD;                    // 2,097,152
    float* E    = hw + (size_t)BB * NN * DD;       // 16,384
    float* F    = E + BB * NN;                     // 16,384
    float* Fs   = F + BB * NN;                     // 16,384
    float* zinv = Fs + BB * NN;                    // 16,384
    int*   perm = (int*)(zinv + BB * NN);          // 16,384
    int*   kk   = perm + BB * NN;                  // 16,384
    float* Q0L  = (float*)(kk + BB * NN);          // 2,097,152
    float* Q1L  = Q0L + (size_t)BB * NN * DD;      // 2,097,152
    float* C0   = Q1L + (size_t)BB * NN * DD;      // 65,536
    float* C1   = C0 + BB * NC * DD;               // 65,536
    float* O0   = C1 + BB * NC * DD;               // 66,560
    float* O1   = O0 + BB * NO * DD;               // 66,560
    unsigned* bar = (unsigned*)(O1 + BB * NO * DD);// 8 counters
    const size_t need = ((char*)(bar + 16) - (char*)ws);   // ~26.4 MB

    if (ws_size < need || d_ws == nullptr) {
        hipMemsetAsync(d_out, 0x42, (size_t)out_size * sizeof(float), stream);
        return;
    }

    hipMemsetAsync(bar, 0, 64, stream);
    GraphAttentionalLayer_1168231104632_mega<<<GRID, TPB, 0, stream>>>(
        h, W, a, out,
        WT, hw, E, F, Fs, zinv, perm, kk,
        Q0L, Q1L, C0, C1, O0, O1, bar);
}

// Round 16
// 108.904 us; speedup vs baseline: 3.4582x; 3.4582x over previous
//
#include <hip/hip_runtime.h>
#include <hip/hip_bf16.h>

#define BB 8
#define NN 2048
#define DD 128
#define TI 32     // i-rows per GEMM block (256 threads)
#define HP 132    // padded row stride for 128-wide LDS tiles
#define CH 32     // chunk length
#define NC (NN / CH)   // 64 chunks per batch
#define NO (NC + 1)    // 65 offset rows (incl. grand total)
#define NFIX (BB * NO) // 520 fix blocks inside mid kernel

__device__ __forceinline__ float relu(float x) { return x > 0.f ? x : 0.f; }

// ---------- Kernel 1: hw = h@W^T ; E=exp(si), F=exp(sj) ----------
// r13-verified structure; W transposed ON THE FLY during LDS staging
// (coalesced global read of W rows, transposed LDS write; 4-way write
// conflict only). Eliminates the separate tr kernel + its dispatch gap.
__global__ __launch_bounds__(256) void GraphAttentionalLayer_1168231104632_kernel(
    const float* __restrict__ h,
    const float* __restrict__ W,
    const float* __restrict__ a,
    float* __restrict__ hw,
    float* __restrict__ E,
    float* __restrict__ F)
{
    __shared__ float h_s[TI][HP];     // 16.9 KB
    __shared__ float wt_s[32][HP];    // 16.9 KB ; wt_s[d2][e] = W[e][dc+d2]

    const int tid = threadIdx.x;
    const int t = tid & 127;
    const int hh = tid >> 7;          // 0/1
    const int tx = tid & 31, ty = tid >> 5;   // ty in 0..7
    const int b = blockIdx.x >> 6;
    const int i0 = (blockIdx.x & 63) * TI;
    const size_t base = ((size_t)b * NN + i0) * DD;

    for (int r = hh; r < TI; r += 2)
        h_s[r][t] = h[base + (size_t)r * DD + t];

    const int e0 = tx * 4, r0 = ty * 4;
    float acc[4][4];
#pragma unroll
    for (int i = 0; i < 4; i++)
#pragma unroll
        for (int j = 0; j < 4; j++) acc[i][j] = 0.f;

    for (int dc = 0; dc < DD; dc += 32) {
        __syncthreads();
        // stage W[0..127][dc..dc+31] transposed into wt_s:
        // g = q*256+tid: e = g>>5 (same for 32 consecutive lanes), d2 = g&31
        // global read coalesced along d; LDS write lane-stride HP (4-way conflict)
#pragma unroll
        for (int q = 0; q < 16; q++) {
            const int g = q * 256 + tid;
            const int e = g >> 5;
            const int d2 = g & 31;
            wt_s[d2][e] = W[(size_t)e * DD + dc + d2];
        }
        __syncthreads();
#pragma unroll 4
        for (int dd = 0; dd < 32; dd++) {
            const float4 wv = *reinterpret_cast<const float4*>(&wt_s[dd][e0]);
            const float w4[4] = {wv.x, wv.y, wv.z, wv.w};
#pragma unroll
            for (int r = 0; r < 4; r++) {
                const float hv = h_s[r0 + r][dc + dd];
#pragma unroll
                for (int e = 0; e < 4; e++) acc[r][e] += hv * w4[e];
            }
        }
    }

#pragma unroll
    for (int r = 0; r < 4; r++) {
        float4 o = make_float4(acc[r][0], acc[r][1], acc[r][2], acc[r][3]);
        *reinterpret_cast<float4*>(&hw[base + (size_t)(r0 + r) * DD + e0]) = o;
    }

    const float4 aiv = *reinterpret_cast<const float4*>(&a[e0]);
    const float4 ajv = *reinterpret_cast<const float4*>(&a[DD + e0]);
    const float ai4[4] = {aiv.x, aiv.y, aiv.z, aiv.w};
    const float aj4[4] = {ajv.x, ajv.y, ajv.z, ajv.w};
#pragma unroll
    for (int r = 0; r < 4; r++) {
        float pi = 0.f, pj = 0.f;
#pragma unroll
        for (int e = 0; e < 4; e++) { pi += acc[r][e] * ai4[e]; pj += acc[r][e] * aj4[e]; }
#pragma unroll
        for (int off = 16; off > 0; off >>= 1) {
            pi += __shfl_down(pi, off, 32);
            pj += __shfl_down(pj, off, 32);
        }
        if (tx == 0) {
            const size_t row = (size_t)b * NN + i0 + r0 + r;
            E[row] = __expf(pi);
            F[row] = __expf(pj);
        }
    }
}

// ---------- Kernel 2: rank-sort, cooperative (r9/r13 verbatim) ----------
__global__ __launch_bounds__(256) void GraphAttentionalLayer_1168231104632_rank(
    const float* __restrict__ F,
    float* __restrict__ Fsorted,
    int* __restrict__ perm)
{
    __shared__ float F_s[NN];
    __shared__ int   part[4][64];

    const int t = threadIdx.x;
    const int b = blockIdx.x >> 5;
    const int j0 = (blockIdx.x & 31) * 64;
    const size_t nb = (size_t)b * NN;

    for (int q = 0; q < NN / 256; q++)
        F_s[q * 256 + t] = F[nb + q * 256 + t];
    __syncthreads();

    const int tj = t & 63, ts = t >> 6;
    const int j = j0 + tj;
    const float fj = F_s[j];
    const int m0 = ts * (NN / 4);
    int cnt = 0;
#pragma unroll 8
    for (int mi = 0; mi < NN / 4; mi++) {
        const int m = m0 + mi;
        const float fm = F_s[m];
        cnt += (fm < fj) | ((fm == fj) & (m < j));
    }
    part[ts][tj] = cnt;
    __syncthreads();
    if (ts == 0) {
        const int r = part[0][tj] + part[1][tj] + part[2][tj] + part[3][tj];
        Fsorted[nb + r] = fj;
        perm[nb + r] = j;
    }
}

// ---------- Kernel 3: chunked prefix scans (r13 verbatim) ----------
__global__ __launch_bounds__(128) void GraphAttentionalLayer_1168231104632_scan(
    const float* __restrict__ hw,
    const float* __restrict__ Fsorted,
    const int* __restrict__ perm,
    float* __restrict__ Q0L, float* __restrict__ Q1L,
    float* __restrict__ C0,  float* __restrict__ C1)
{
    const int t = threadIdx.x;
    const int b = blockIdx.x / NC, c = blockIdx.x % NC;
    const size_t nb = (size_t)b * NN;
    const int m0 = c * CH;

    int   jv[CH];
    float Fv[CH];
#pragma unroll
    for (int mm = 0; mm < CH; mm++) jv[mm] = perm[nb + m0 + mm];
#pragma unroll
    for (int mm = 0; mm < CH; mm++) Fv[mm] = Fsorted[nb + m0 + mm];

    float hv[CH];
#pragma unroll
    for (int mm = 0; mm < CH; mm++)
        hv[mm] = hw[(nb + jv[mm]) * DD + t];

    float a0 = 0.f, a1 = 0.f;
#pragma unroll
    for (int mm = 0; mm < CH; mm++) {
        const int m = m0 + mm;
        Q0L[(nb + m) * DD + t] = a0;
        Q1L[(nb + m) * DD + t] = a1;
        a0 += hv[mm];
        a1 += Fv[mm] * hv[mm];
    }
    C0[((size_t)b * NC + c) * DD + t] = a0;
    C1[((size_t)b * NC + c) * DD + t] = a1;
}

// ---------- Kernel 4 (mid): fix offsets + parallel LDS search (r13 verbatim) ----------
__global__ __launch_bounds__(256) void GraphAttentionalLayer_1168231104632_mid(
    const float* __restrict__ C0, const float* __restrict__ C1,
    const float* __restrict__ Fsorted, const float* __restrict__ E,
    float* __restrict__ O0, float* __restrict__ O1,
    int* __restrict__ kk,  float* __restrict__ zinv)
{
    __shared__ float fs_s[NN];      // 8 KB
    __shared__ float cf_s[NC];
    __shared__ float of_s[NO];

    const int tid = threadIdx.x;

    if (blockIdx.x < NFIX) {
        const int b = blockIdx.x / NO, c = blockIdx.x % NO;
        const int d = tid & 127;
        const float* C = (tid < 128) ? C0 : C1;
        float*       O = (tid < 128) ? O0 : O1;
        float o = 0.f;
        int c2 = 0;
        for (; c2 + 16 <= c; c2 += 16) {
            float v[16];
#pragma unroll
            for (int q = 0; q < 16; q++)
                v[q] = C[((size_t)b * NC + c2 + q) * DD + d];
#pragma unroll
            for (int q = 0; q < 16; q++) o += v[q];
        }
        for (; c2 < c; c2++)
            o += C[((size_t)b * NC + c2) * DD + d];
        O[((size_t)b * NO + c) * DD + d] = o;
        return;
    }

    const int sb = blockIdx.x - NFIX;
    const int b = sb >> 3;
    const int i0 = (sb & 7) * 256;
    const size_t nb = (size_t)b * NN;

    for (int q = 0; q < NN / 256; q++)
        fs_s[q * 256 + tid] = Fsorted[nb + q * 256 + tid];
    __syncthreads();

    if (tid < NC) {
        float p = 0.f;
        const int m0 = tid * CH;
#pragma unroll
        for (int mm = 0; mm < CH; mm++) p += fs_s[m0 + mm];
        cf_s[tid] = p;
    }
    __syncthreads();
    if (tid < NO) {
        float p = 0.f;
        for (int c2 = 0; c2 < tid; c2++) p += cf_s[c2];
        of_s[tid] = p;
    }
    __syncthreads();

    const int row = (int)nb + i0 + tid;
    const float Ei = E[row];
    const float thr = 1.0f / Ei;
    int lo = 0, hi = NN;
    while (lo < hi) {
        const int mid = (lo + hi) >> 1;
        if (fs_s[mid] < thr) lo = mid + 1; else hi = mid;
    }
    float fpl = 0.f;
    for (int m = (lo >> 5) << 5; m < lo; m++) fpl += fs_s[m];
    const float TF = of_s[NC];
    const float Pk = of_s[lo >> 5] + fpl;
    const float z = Ei * (TF - Pk) + (float)lo;
    kk[row] = lo;
    zinv[row] = 1.0f / z;
}

// ---------- Kernel 5: output (r13 verbatim: one block per i-row) ----------
__global__ __launch_bounds__(128) void GraphAttentionalLayer_1168231104632_out(
    const float* __restrict__ Q0L, const float* __restrict__ Q1L,
    const float* __restrict__ O0,  const float* __restrict__ O1,
    const int* __restrict__ kk,    const float* __restrict__ zinv,
    const float* __restrict__ E,   float* __restrict__ out)
{
    const int t = threadIdx.x;
    const int row = blockIdx.x;          // 0 .. BB*NN-1
    const int b = row >> 11;
    const size_t nb = (size_t)b * NN;

    const int k = kk[row];               // uniform
    const float Ev = E[row];
    const float zv = zinv[row];
    const float T1 = O1[((size_t)b * NO + NC) * DD + t];

    float num;
    if (k < NN) {
        const int c = k >> 5;
        const float q0 = Q0L[(nb + k) * DD + t] + O0[((size_t)b * NO + c) * DD + t];
        const float q1 = Q1L[(nb + k) * DD + t] + O1[((size_t)b * NO + c) * DD + t];
        num = Ev * (T1 - q1) + q0;
    } else {
        num = O0[((size_t)b * NO + NC) * DD + t];
    }
    out[(size_t)row * DD + t] = relu(num * zv);
}

extern "C" __attribute__((visibility("default")))
void kernel_launch(void* const* d_in, const int* in_sizes, int n_in,
                   void* d_out, int out_size, void* d_ws, size_t ws_size,
                   hipStream_t stream) {
    const float* h = nullptr; const float* W = nullptr; const float* a = nullptr;
    for (int i = 0; i < n_in; i++) {
        if (in_sizes[i] == BB * NN * DD)      h = (const float*)d_in[i];
        else if (in_sizes[i] == DD * DD)      W = (const float*)d_in[i];
        else if (in_sizes[i] == 2 * DD)       a = (const float*)d_in[i];
    }
    if (!h) h = (const float*)d_in[0];
    if (!W) W = (const float*)d_in[1];
    if (!a) a = (const float*)d_in[2];

    float* out = (float*)d_out;
    float* ws = (float*)d_ws;

    float* hw   = ws;                              // 2,097,152
    float* E    = hw + (size_t)BB * NN * DD;       // 16,384
    float* F    = E + BB * NN;                     // 16,384
    float* Fs   = F + BB * NN;                     // 16,384
    float* zinv = Fs + BB * NN;                    // 16,384
    int*   perm = (int*)(zinv + BB * NN);          // 16,384
    int*   kk   = perm + BB * NN;                  // 16,384
    float* Q0L  = (float*)(kk + BB * NN);          // 2,097,152
    float* Q1L  = Q0L + (size_t)BB * NN * DD;      // 2,097,152
    float* C0   = Q1L + (size_t)BB * NN * DD;      // 65,536
    float* C1   = C0 + BB * NC * DD;               // 65,536
    float* O0   = C1 + BB * NC * DD;               // 66,560
    float* O1   = O0 + BB * NO * DD;               // 66,560
    const size_t need = (size_t)((O1 + BB * NO * DD) - ws) * sizeof(float); // ~26.3 MB

    if (ws_size < need || d_ws == nullptr) {
        hipMemsetAsync(d_out, 0x42, (size_t)out_size * sizeof(float), stream);
        return;
    }

    GraphAttentionalLayer_1168231104632_kernel<<<BB * (NN / TI), 256, 0, stream>>>(h, W, a, hw, E, F);
    GraphAttentionalLayer_1168231104632_rank<<<BB * 32, 256, 0, stream>>>(F, Fs, perm);
    GraphAttentionalLayer_1168231104632_scan<<<BB * NC, 128, 0, stream>>>(hw, Fs, perm, Q0L, Q1L, C0, C1);
    GraphAttentionalLayer_1168231104632_mid<<<NFIX + BB * 8, 256, 0, stream>>>(C0, C1, Fs, E, O0, O1, kk, zinv);
    GraphAttentionalLayer_1168231104632_out<<<BB * NN, 128, 0, stream>>>(Q0L, Q1L, O0, O1, kk, zinv, E, out);
}